// Round 7
// baseline (235.897 us; speedup 1.0000x reference)
//
#include <hip/hip_runtime.h>
#include <hip/hip_bf16.h>
#include <stdint.h>

#define B_ 32
#define T_ 128
#define S_ 2048
#define D_ 1024

typedef float floatx4 __attribute__((ext_vector_type(4)));
typedef float f32x4 __attribute__((ext_vector_type(4)));
typedef unsigned short u16x4 __attribute__((ext_vector_type(4)));
typedef unsigned short u16x8 __attribute__((ext_vector_type(8)));
typedef __bf16 bf16x8 __attribute__((ext_vector_type(8)));

__device__ __forceinline__ unsigned short f2bf(float x){
  __hip_bfloat16 h = __float2bfloat16(x);
  return __builtin_bit_cast(unsigned short, h);
}
__device__ __forceinline__ float bf2f(unsigned short u){
  __hip_bfloat16 h = __builtin_bit_cast(__hip_bfloat16, u);
  return __bfloat162float(h);
}
__device__ __forceinline__ f32x4 mfma16(u16x8 a, u16x8 b, f32x4 c){
  return __builtin_amdgcn_mfma_f32_16x16x32_bf16(
      __builtin_bit_cast(bf16x8, a), __builtin_bit_cast(bf16x8, b), c, 0, 0, 0);
}

// ---------------------------------------------------------------------------
// K1: logits[b][t][s] = sum_d src[b][t][d] * mb[b][s][d]
// Round-4 verified structure (RNE hi/lo split x 3 MFMA, BK=32, 1-deep
// prefetch, 2-barrier single-buffer). GEOMETRY ONLY changed: tile 128t x 64s,
// 256 threads (4 waves, 2x2 grid of the same 64x32 wave tile), grid 32x32 =
// 1024 blocks -> 4 blocks/CU (LDS 30 KB). More independent barrier-groups
// per CU hides the per-step latency that made all pipes idle.
// ---------------------------------------------------------------------------
__global__ __launch_bounds__(256, 4) void k_align(
    const float* __restrict__ src, const float* __restrict__ mb,
    float* __restrict__ logits)
{
  __shared__ unsigned short Ah[128][40], Al[128][40];
  __shared__ unsigned short Bh[64][40],  Bl[64][40];
  const int b = blockIdx.x, sblk = blockIdx.y;      // sblk: 64 s-rows each
  const int tid = threadIdx.x, lane = tid & 63, wave = tid >> 6;  // 4 waves
  const int wr = wave >> 1, wc = wave & 1;          // 2x2 wave grid
  const float* Ag = src + (size_t)b * T_ * D_;
  const float* Bg = mb + (size_t)b * S_ * D_ + (size_t)sblk * 64 * D_;

  f32x4 acc[4][2];
  #pragma unroll
  for (int m = 0; m < 4; m++)
    #pragma unroll
    for (int n = 0; n < 2; n++) acc[m][n] = (f32x4){0.f, 0.f, 0.f, 0.f};

  // A staging: [128 rows][8 float4] = 1024 f4, 4/thread.
  // B staging: [ 64 rows][8 float4] =  512 f4, 2/thread.
  floatx4 ra[4], rb[2];
  #pragma unroll
  for (int j = 0; j < 4; j++) {
    int f4 = tid + 256 * j;
    int row = f4 >> 3, c4 = (f4 & 7) * 4;
    ra[j] = *(const floatx4*)(Ag + (size_t)row * D_ + c4);
  }
  #pragma unroll
  for (int j = 0; j < 2; j++) {
    int f4 = tid + 256 * j;
    int row = f4 >> 3, c4 = (f4 & 7) * 4;
    rb[j] = *(const floatx4*)(Bg + (size_t)row * D_ + c4);
  }

  for (int k0 = 0; k0 < D_; k0 += 32) {
    // convert staged regs -> LDS (RNE hi/lo split, identical math to R4)
    #pragma unroll
    for (int j = 0; j < 4; j++) {
      int f4 = tid + 256 * j;
      int row = f4 >> 3, c4 = (f4 & 7) * 4;
      u16x4 ah, al;
      #pragma unroll
      for (int i = 0; i < 4; i++) {
        unsigned short h = f2bf(ra[j][i]); float hf = bf2f(h);
        ah[i] = h; al[i] = f2bf(ra[j][i] - hf);
      }
      *(u16x4*)&Ah[row][c4] = ah;
      *(u16x4*)&Al[row][c4] = al;
    }
    #pragma unroll
    for (int j = 0; j < 2; j++) {
      int f4 = tid + 256 * j;
      int row = f4 >> 3, c4 = (f4 & 7) * 4;
      u16x4 bh, bl;
      #pragma unroll
      for (int i = 0; i < 4; i++) {
        unsigned short h = f2bf(rb[j][i]); float hf = bf2f(h);
        bh[i] = h; bl[i] = f2bf(rb[j][i] - hf);
      }
      *(u16x4*)&Bh[row][c4] = bh;
      *(u16x4*)&Bl[row][c4] = bl;
    }
    __syncthreads();
    // prefetch next K-tile (in flight during MFMA phase)
    if (k0 + 32 < D_) {
      #pragma unroll
      for (int j = 0; j < 4; j++) {
        int f4 = tid + 256 * j;
        int row = f4 >> 3, c4 = (f4 & 7) * 4;
        ra[j] = *(const floatx4*)(Ag + (size_t)row * D_ + (k0 + 32) + c4);
      }
      #pragma unroll
      for (int j = 0; j < 2; j++) {
        int f4 = tid + 256 * j;
        int row = f4 >> 3, c4 = (f4 & 7) * 4;
        rb[j] = *(const floatx4*)(Bg + (size_t)row * D_ + (k0 + 32) + c4);
      }
    }
    {
      const int kb = (lane >> 4) << 3;
      u16x8 a_h[4], a_l[4], b_h[2], b_l[2];
      #pragma unroll
      for (int m = 0; m < 4; m++) {
        int r = wr * 64 + m * 16 + (lane & 15);
        a_h[m] = *(const u16x8*)&Ah[r][kb];
        a_l[m] = *(const u16x8*)&Al[r][kb];
      }
      #pragma unroll
      for (int n = 0; n < 2; n++) {
        int r = wc * 32 + n * 16 + (lane & 15);
        b_h[n] = *(const u16x8*)&Bh[r][kb];
        b_l[n] = *(const u16x8*)&Bl[r][kb];
      }
      #pragma unroll
      for (int m = 0; m < 4; m++)
        #pragma unroll
        for (int n = 0; n < 2; n++) {
          acc[m][n] = mfma16(a_h[m], b_h[n], acc[m][n]);
          acc[m][n] = mfma16(a_h[m], b_l[n], acc[m][n]);
          acc[m][n] = mfma16(a_l[m], b_h[n], acc[m][n]);
        }
    }
    __syncthreads();
  }
  #pragma unroll
  for (int m = 0; m < 4; m++)
    #pragma unroll
    for (int n = 0; n < 2; n++)
      #pragma unroll
      for (int j = 0; j < 4; j++) {
        int t = wr * 64 + m * 16 + ((lane >> 4) << 2) + j;
        int s = sblk * 64 + wc * 32 + n * 16 + (lane & 15);
        logits[((size_t)b * T_ + t) * S_ + s] = acc[m][n][j];
      }
}

// ---------------------------------------------------------------------------
// K2: masked softmax per (b,t) row; writes p in-place over logits (for K3)
// and transposed to out1[t][b][s].  (verified, unchanged)
// ---------------------------------------------------------------------------
__global__ __launch_bounds__(256) void k_softmax(
    float* __restrict__ logits, const int* __restrict__ lens,
    float* __restrict__ out1)
{
  const int bt = blockIdx.x;
  const int b = bt >> 7, t = bt & 127;
  const int probe = lens[1];               // 0 iff int64 layout (lens>=1)
  const int len = (probe == 0) ? lens[2 * b] : lens[b];
  float* row = logits + (size_t)bt * S_;
  const int tid = threadIdx.x, lane = tid & 63, wave = tid >> 6;

  floatx4 v[2];
  float mx = -3.0e38f;
  #pragma unroll
  for (int j = 0; j < 2; j++) {
    int f4 = tid + 256 * j;
    v[j] = *(const floatx4*)(row + f4 * 4);
    #pragma unroll
    for (int i = 0; i < 4; i++) {
      int s = f4 * 4 + i;
      if (s < len) mx = fmaxf(mx, v[j][i]);
    }
  }
  #pragma unroll
  for (int off = 1; off < 64; off <<= 1) mx = fmaxf(mx, __shfl_xor(mx, off));
  __shared__ float red[8];
  if (lane == 0) red[wave] = mx;
  __syncthreads();
  mx = fmaxf(fmaxf(red[0], red[1]), fmaxf(red[2], red[3]));

  float sum = 0.f;
  floatx4 e[2];
  #pragma unroll
  for (int j = 0; j < 2; j++) {
    int f4 = tid + 256 * j;
    #pragma unroll
    for (int i = 0; i < 4; i++) {
      int s = f4 * 4 + i;
      float ee = (s < len) ? __expf(v[j][i] - mx) : 0.f;
      e[j][i] = ee; sum += ee;
    }
  }
  #pragma unroll
  for (int off = 1; off < 64; off <<= 1) sum += __shfl_xor(sum, off);
  if (lane == 0) red[4 + wave] = sum;
  __syncthreads();
  sum = red[4] + red[5] + red[6] + red[7];
  const float inv = 1.0f / sum;

  float* orow = out1 + ((size_t)t * B_ + b) * S_;
  #pragma unroll
  for (int j = 0; j < 2; j++) {
    int f4 = tid + 256 * j;
    floatx4 o;
    #pragma unroll
    for (int i = 0; i < 4; i++) o[i] = e[j][i] * inv;
    *(floatx4*)(row + f4 * 4) = o;
    *(floatx4*)(orow + f4 * 4) = o;
  }
}

// ---------------------------------------------------------------------------
// K3: c[b][t][d] = sum_s p[b][t][s] * mb[b][s][d].  (round-4 verified,
// no S-split — the split regressed in round 6)
// ---------------------------------------------------------------------------
__global__ __launch_bounds__(512, 2) void k_pv(
    const float* __restrict__ p, const float* __restrict__ mb,
    float* __restrict__ cout)
{
  __shared__ unsigned short As[128][72];   // [t][s]
  __shared__ unsigned short BsT[128][72];  // [d][s]
  const int b = blockIdx.x, dblk = blockIdx.y;
  const int tid = threadIdx.x, lane = tid & 63, wave = tid >> 6;
  const int wr = wave >> 2, wc = wave & 3;
  const float* Pg = p + (size_t)b * T_ * S_;
  const float* Bg = mb + (size_t)b * S_ * D_ + dblk * 128;

  f32x4 acc[4][2];
  #pragma unroll
  for (int m = 0; m < 4; m++)
    #pragma unroll
    for (int n = 0; n < 2; n++) acc[m][n] = (f32x4){0.f, 0.f, 0.f, 0.f};

  const int gs = tid & 15, gd = tid >> 4;  // transpose group: 4s x 4d
  const int s0 = gs * 4, d0 = gd * 4;

  floatx4 ra[4], rb[4];
  #pragma unroll
  for (int j = 0; j < 4; j++) {
    int f4 = tid + 512 * j;
    int row = f4 >> 4, c4 = (f4 & 15) * 4;
    ra[j] = *(const floatx4*)(Pg + (size_t)row * S_ + c4);
    rb[j] = *(const floatx4*)(Bg + (size_t)(s0 + j) * D_ + d0);
  }

  for (int k0 = 0; k0 < S_; k0 += 64) {
    #pragma unroll
    for (int j = 0; j < 4; j++) {
      int f4 = tid + 512 * j;
      int row = f4 >> 4, c4 = (f4 & 15) * 4;
      u16x4 ah;
      #pragma unroll
      for (int i = 0; i < 4; i++) ah[i] = f2bf(ra[j][i]);
      *(u16x4*)&As[row][c4] = ah;
    }
    #pragma unroll
    for (int jj = 0; jj < 4; jj++) {
      u16x4 w = { f2bf(rb[0][jj]), f2bf(rb[1][jj]), f2bf(rb[2][jj]), f2bf(rb[3][jj]) };
      *(u16x4*)&BsT[d0 + jj][s0] = w;
    }
    __syncthreads();
    if (k0 + 64 < S_) {
      #pragma unroll
      for (int j = 0; j < 4; j++) {
        int f4 = tid + 512 * j;
        int row = f4 >> 4, c4 = (f4 & 15) * 4;
        ra[j] = *(const floatx4*)(Pg + (size_t)row * S_ + (k0 + 64) + c4);
        rb[j] = *(const floatx4*)(Bg + (size_t)(k0 + 64 + s0 + j) * D_ + d0);
      }
    }
    #pragma unroll
    for (int kk = 0; kk < 2; kk++) {
      int kb = kk * 32 + ((lane >> 4) << 3);
      u16x8 a[4], bb[2];
      #pragma unroll
      for (int m = 0; m < 4; m++)
        a[m] = *(const u16x8*)&As[wr * 64 + m * 16 + (lane & 15)][kb];
      #pragma unroll
      for (int n = 0; n < 2; n++)
        bb[n] = *(const u16x8*)&BsT[wc * 32 + n * 16 + (lane & 15)][kb];
      #pragma unroll
      for (int m = 0; m < 4; m++)
        #pragma unroll
        for (int n = 0; n < 2; n++)
          acc[m][n] = mfma16(a[m], bb[n], acc[m][n]);
    }
    __syncthreads();
  }
  #pragma unroll
  for (int m = 0; m < 4; m++)
    #pragma unroll
    for (int n = 0; n < 2; n++)
      #pragma unroll
      for (int j = 0; j < 4; j++) {
        int t = wr * 64 + m * 16 + ((lane >> 4) << 2) + j;
        int d = dblk * 128 + wc * 32 + n * 16 + (lane & 15);
        cout[((size_t)b * T_ + t) * D_ + d] = acc[m][n][j];
      }
}

// ---------------------------------------------------------------------------
// K4: attn_h[t][b][n] = tanh( sum_k [c,src][b][t][k] * W[n][k] )
// (round-4 verified, single-c)
// ---------------------------------------------------------------------------
__global__ __launch_bounds__(512, 2) void k_proj(
    const float* __restrict__ cbuf, const float* __restrict__ src,
    const float* __restrict__ w, float* __restrict__ out0)
{
  __shared__ unsigned short Ah[128][72], Bh[128][72];
  const int b = blockIdx.x, nblk = blockIdx.y;
  const int tid = threadIdx.x, lane = tid & 63, wave = tid >> 6;
  const int wr = wave >> 2, wc = wave & 3;
  const float* Ca = cbuf + (size_t)b * T_ * D_;
  const float* Sa = src + (size_t)b * T_ * D_;

  f32x4 acc[4][2];
  #pragma unroll
  for (int m = 0; m < 4; m++)
    #pragma unroll
    for (int n = 0; n < 2; n++) acc[m][n] = (f32x4){0.f, 0.f, 0.f, 0.f};

  floatx4 ra[4], rb[4];
  #pragma unroll
  for (int j = 0; j < 4; j++) {
    int f4 = tid + 512 * j;
    int row = f4 >> 4, c4 = (f4 & 15) * 4;
    ra[j] = *(const floatx4*)(Ca + (size_t)row * D_ + c4);
    rb[j] = *(const floatx4*)(w + (size_t)(nblk * 128 + row) * (2 * D_) + c4);
  }

  for (int k0 = 0; k0 < 2 * D_; k0 += 64) {
    #pragma unroll
    for (int j = 0; j < 4; j++) {
      int f4 = tid + 512 * j;
      int row = f4 >> 4, c4 = (f4 & 15) * 4;
      u16x4 ah, bh;
      #pragma unroll
      for (int i = 0; i < 4; i++) { ah[i] = f2bf(ra[j][i]); bh[i] = f2bf(rb[j][i]); }
      *(u16x4*)&Ah[row][c4] = ah;
      *(u16x4*)&Bh[row][c4] = bh;
    }
    __syncthreads();
    if (k0 + 64 < 2 * D_) {
      int kn = k0 + 64;
      const float* Asrc = (kn < D_) ? (Ca + kn) : (Sa + (kn - D_));
      #pragma unroll
      for (int j = 0; j < 4; j++) {
        int f4 = tid + 512 * j;
        int row = f4 >> 4, c4 = (f4 & 15) * 4;
        ra[j] = *(const floatx4*)(Asrc + (size_t)row * D_ + c4);
        rb[j] = *(const floatx4*)(w + (size_t)(nblk * 128 + row) * (2 * D_) + kn + c4);
      }
    }
    #pragma unroll
    for (int kk = 0; kk < 2; kk++) {
      int kb = kk * 32 + ((lane >> 4) << 3);
      u16x8 a[4], bb[2];
      #pragma unroll
      for (int m = 0; m < 4; m++)
        a[m] = *(const u16x8*)&Ah[wr * 64 + m * 16 + (lane & 15)][kb];
      #pragma unroll
      for (int n = 0; n < 2; n++)
        bb[n] = *(const u16x8*)&Bh[wc * 32 + n * 16 + (lane & 15)][kb];
      #pragma unroll
      for (int m = 0; m < 4; m++)
        #pragma unroll
        for (int n = 0; n < 2; n++)
          acc[m][n] = mfma16(a[m], bb[n], acc[m][n]);
    }
    __syncthreads();
  }
  #pragma unroll
  for (int m = 0; m < 4; m++)
    #pragma unroll
    for (int n = 0; n < 2; n++)
      #pragma unroll
      for (int j = 0; j < 4; j++) {
        int t = wr * 64 + m * 16 + ((lane >> 4) << 2) + j;
        int d = nblk * 128 + wc * 32 + n * 16 + (lane & 15);
        out0[(size_t)t * (B_ * D_) + (size_t)b * D_ + d] = tanhf(acc[m][n][j]);
      }
}

extern "C" void kernel_launch(void* const* d_in, const int* in_sizes, int n_in,
                              void* d_out, int out_size, void* d_ws, size_t ws_size,
                              hipStream_t stream) {
  const float* src = (const float*)d_in[0];   // [B][T][D]
  const float* mb  = (const float*)d_in[1];   // [B][S][D]
  const float* w   = (const float*)d_in[2];   // [D][2D]
  const int*   len = (const int*)d_in[3];     // [B]

  float* out0 = (float*)d_out;                       // attn_h [T][B][D]
  float* out1 = out0 + (size_t)T_ * B_ * D_;         // align  [T][B][S]

  float* logits = (float*)d_ws;                      // [B][T][S] fp32
  float* cbuf   = logits + (size_t)B_ * T_ * S_;     // [B][T][D] fp32

  k_align  <<<dim3(B_, S_ / 64),  256, 0, stream>>>(src, mb, logits);
  k_softmax<<<dim3(B_ * T_),      256, 0, stream>>>(logits, len, out1);
  k_pv     <<<dim3(B_, D_ / 128), 512, 0, stream>>>(logits, mb, cbuf);
  k_proj   <<<dim3(B_, D_ / 128), 512, 0, stream>>>(cbuf, src, w, out0);
}

// Round 8
// 221.980 us; speedup vs baseline: 1.0627x; 1.0627x over previous
//
#include <hip/hip_runtime.h>
#include <hip/hip_bf16.h>
#include <stdint.h>

#define B_ 32
#define T_ 128
#define S_ 2048
#define D_ 1024

typedef float floatx4 __attribute__((ext_vector_type(4)));
typedef float f32x4 __attribute__((ext_vector_type(4)));
typedef unsigned short u16x4 __attribute__((ext_vector_type(4)));
typedef unsigned short u16x8 __attribute__((ext_vector_type(8)));
typedef __bf16 bf16x8 __attribute__((ext_vector_type(8)));

__device__ __forceinline__ unsigned short f2bf(float x){
  __hip_bfloat16 h = __float2bfloat16(x);
  return __builtin_bit_cast(unsigned short, h);
}
__device__ __forceinline__ float bf2f(unsigned short u){
  __hip_bfloat16 h = __builtin_bit_cast(__hip_bfloat16, u);
  return __bfloat162float(h);
}
__device__ __forceinline__ f32x4 mfma16(u16x8 a, u16x8 b, f32x4 c){
  return __builtin_amdgcn_mfma_f32_16x16x32_bf16(
      __builtin_bit_cast(bf16x8, a), __builtin_bit_cast(bf16x8, b), c, 0, 0, 0);
}

// ---------------------------------------------------------------------------
// K1: logits[b][t][s] = sum_d src[b][t][d] * mb[b][s][d]
// EXACT round-4 verified version (RNE hi/lo split x 3 MFMA, BK=32, 1-deep
// prefetch, 2-barrier single-buffer, 128x128 tile, 512 thr, LDS 40KB->2/CU).
// ---------------------------------------------------------------------------
__global__ __launch_bounds__(512, 4) void k_align(
    const float* __restrict__ src, const float* __restrict__ mb,
    float* __restrict__ logits)
{
  __shared__ unsigned short Ah[128][40], Al[128][40], Bh[128][40], Bl[128][40];
  const int b = blockIdx.x, sblk = blockIdx.y;
  const int tid = threadIdx.x, lane = tid & 63, wave = tid >> 6;
  const int wr = wave >> 2, wc = wave & 3;
  const float* Ag = src + (size_t)b * T_ * D_;
  const float* Bg = mb + (size_t)b * S_ * D_ + (size_t)sblk * 128 * D_;

  f32x4 acc[4][2];
  #pragma unroll
  for (int m = 0; m < 4; m++)
    #pragma unroll
    for (int n = 0; n < 2; n++) acc[m][n] = (f32x4){0.f, 0.f, 0.f, 0.f};

  floatx4 ra[2], rb[2];
  #pragma unroll
  for (int j = 0; j < 2; j++) {
    int f4 = tid + 512 * j;
    int row = f4 >> 3, c4 = (f4 & 7) * 4;
    ra[j] = *(const floatx4*)(Ag + (size_t)row * D_ + c4);
    rb[j] = *(const floatx4*)(Bg + (size_t)row * D_ + c4);
  }

  for (int k0 = 0; k0 < D_; k0 += 32) {
    #pragma unroll
    for (int j = 0; j < 2; j++) {
      int f4 = tid + 512 * j;
      int row = f4 >> 3, c4 = (f4 & 7) * 4;
      u16x4 ah, al, bh, bl;
      #pragma unroll
      for (int i = 0; i < 4; i++) {
        unsigned short h = f2bf(ra[j][i]); float hf = bf2f(h);
        ah[i] = h; al[i] = f2bf(ra[j][i] - hf);
        h = f2bf(rb[j][i]); hf = bf2f(h);
        bh[i] = h; bl[i] = f2bf(rb[j][i] - hf);
      }
      *(u16x4*)&Ah[row][c4] = ah;
      *(u16x4*)&Al[row][c4] = al;
      *(u16x4*)&Bh[row][c4] = bh;
      *(u16x4*)&Bl[row][c4] = bl;
    }
    __syncthreads();
    if (k0 + 32 < D_) {
      #pragma unroll
      for (int j = 0; j < 2; j++) {
        int f4 = tid + 512 * j;
        int row = f4 >> 3, c4 = (f4 & 7) * 4;
        ra[j] = *(const floatx4*)(Ag + (size_t)row * D_ + (k0 + 32) + c4);
        rb[j] = *(const floatx4*)(Bg + (size_t)row * D_ + (k0 + 32) + c4);
      }
    }
    {
      const int kb = (lane >> 4) << 3;
      u16x8 a_h[4], a_l[4], b_h[2], b_l[2];
      #pragma unroll
      for (int m = 0; m < 4; m++) {
        int r = wr * 64 + m * 16 + (lane & 15);
        a_h[m] = *(const u16x8*)&Ah[r][kb];
        a_l[m] = *(const u16x8*)&Al[r][kb];
      }
      #pragma unroll
      for (int n = 0; n < 2; n++) {
        int r = wc * 32 + n * 16 + (lane & 15);
        b_h[n] = *(const u16x8*)&Bh[r][kb];
        b_l[n] = *(const u16x8*)&Bl[r][kb];
      }
      #pragma unroll
      for (int m = 0; m < 4; m++)
        #pragma unroll
        for (int n = 0; n < 2; n++) {
          acc[m][n] = mfma16(a_h[m], b_h[n], acc[m][n]);
          acc[m][n] = mfma16(a_h[m], b_l[n], acc[m][n]);
          acc[m][n] = mfma16(a_l[m], b_h[n], acc[m][n]);
        }
    }
    __syncthreads();
  }
  #pragma unroll
  for (int m = 0; m < 4; m++)
    #pragma unroll
    for (int n = 0; n < 2; n++)
      #pragma unroll
      for (int j = 0; j < 4; j++) {
        int t = wr * 64 + m * 16 + ((lane >> 4) << 2) + j;
        int s = sblk * 128 + wc * 32 + n * 16 + (lane & 15);
        logits[((size_t)b * T_ + t) * S_ + s] = acc[m][n][j];
      }
}

// ---------------------------------------------------------------------------
// K2: masked softmax per (b,t) row (verified, unchanged).
// ---------------------------------------------------------------------------
__global__ __launch_bounds__(256) void k_softmax(
    float* __restrict__ logits, const int* __restrict__ lens,
    float* __restrict__ out1)
{
  const int bt = blockIdx.x;
  const int b = bt >> 7, t = bt & 127;
  const int probe = lens[1];               // 0 iff int64 layout (lens>=1)
  const int len = (probe == 0) ? lens[2 * b] : lens[b];
  float* row = logits + (size_t)bt * S_;
  const int tid = threadIdx.x, lane = tid & 63, wave = tid >> 6;

  floatx4 v[2];
  float mx = -3.0e38f;
  #pragma unroll
  for (int j = 0; j < 2; j++) {
    int f4 = tid + 256 * j;
    v[j] = *(const floatx4*)(row + f4 * 4);
    #pragma unroll
    for (int i = 0; i < 4; i++) {
      int s = f4 * 4 + i;
      if (s < len) mx = fmaxf(mx, v[j][i]);
    }
  }
  #pragma unroll
  for (int off = 1; off < 64; off <<= 1) mx = fmaxf(mx, __shfl_xor(mx, off));
  __shared__ float red[8];
  if (lane == 0) red[wave] = mx;
  __syncthreads();
  mx = fmaxf(fmaxf(red[0], red[1]), fmaxf(red[2], red[3]));

  float sum = 0.f;
  floatx4 e[2];
  #pragma unroll
  for (int j = 0; j < 2; j++) {
    int f4 = tid + 256 * j;
    #pragma unroll
    for (int i = 0; i < 4; i++) {
      int s = f4 * 4 + i;
      float ee = (s < len) ? __expf(v[j][i] - mx) : 0.f;
      e[j][i] = ee; sum += ee;
    }
  }
  #pragma unroll
  for (int off = 1; off < 64; off <<= 1) sum += __shfl_xor(sum, off);
  if (lane == 0) red[4 + wave] = sum;
  __syncthreads();
  sum = red[4] + red[5] + red[6] + red[7];
  const float inv = 1.0f / sum;

  float* orow = out1 + ((size_t)t * B_ + b) * S_;
  #pragma unroll
  for (int j = 0; j < 2; j++) {
    int f4 = tid + 256 * j;
    floatx4 o;
    #pragma unroll
    for (int i = 0; i < 4; i++) o[i] = e[j][i] * inv;
    *(floatx4*)(row + f4 * 4) = o;
    *(floatx4*)(orow + f4 * 4) = o;
  }
}

// ---------------------------------------------------------------------------
// K3: c[b][t][d] = sum_s p[b][t][s] * mb[b][s][d].
// Round-4 inner structure; GEOMETRY: 256 thr (4 waves 2x2, wave 64x32),
// d-tile 64 -> grid (B,16) = 512 blocks = 2 blocks/CU (p is L2-resident
// per b, so the doubled A re-staging costs no HBM traffic).
// ---------------------------------------------------------------------------
__global__ __launch_bounds__(256, 2) void k_pv(
    const float* __restrict__ p, const float* __restrict__ mb,
    float* __restrict__ cout)
{
  __shared__ unsigned short As[128][72];   // [t][s]
  __shared__ unsigned short BsT[64][72];   // [d][s]
  const int b = blockIdx.x, dblk = blockIdx.y;   // dblk: 64 d each
  const int tid = threadIdx.x, lane = tid & 63, wave = tid >> 6;
  const int wr = wave >> 1, wc = wave & 1;       // 2x2 wave grid
  const float* Pg = p + (size_t)b * T_ * S_;
  const float* Bg = mb + (size_t)b * S_ * D_ + dblk * 64;

  f32x4 acc[4][2];
  #pragma unroll
  for (int m = 0; m < 4; m++)
    #pragma unroll
    for (int n = 0; n < 2; n++) acc[m][n] = (f32x4){0.f, 0.f, 0.f, 0.f};

  const int gs = tid & 15, gd = tid >> 4;  // transpose group: 4s x 4d
  const int s0 = gs * 4, d0 = gd * 4;      // both 0..60

  floatx4 ra[8], rb[4];
  #pragma unroll
  for (int j = 0; j < 8; j++) {
    int f4 = tid + 256 * j;
    int row = f4 >> 4, c4 = (f4 & 15) * 4;
    ra[j] = *(const floatx4*)(Pg + (size_t)row * S_ + c4);
  }
  #pragma unroll
  for (int j = 0; j < 4; j++)
    rb[j] = *(const floatx4*)(Bg + (size_t)(s0 + j) * D_ + d0);

  for (int k0 = 0; k0 < S_; k0 += 64) {
    #pragma unroll
    for (int j = 0; j < 8; j++) {
      int f4 = tid + 256 * j;
      int row = f4 >> 4, c4 = (f4 & 15) * 4;
      u16x4 ah;
      #pragma unroll
      for (int i = 0; i < 4; i++) ah[i] = f2bf(ra[j][i]);
      *(u16x4*)&As[row][c4] = ah;
    }
    #pragma unroll
    for (int jj = 0; jj < 4; jj++) {
      u16x4 w = { f2bf(rb[0][jj]), f2bf(rb[1][jj]), f2bf(rb[2][jj]), f2bf(rb[3][jj]) };
      *(u16x4*)&BsT[d0 + jj][s0] = w;
    }
    __syncthreads();
    if (k0 + 64 < S_) {
      #pragma unroll
      for (int j = 0; j < 8; j++) {
        int f4 = tid + 256 * j;
        int row = f4 >> 4, c4 = (f4 & 15) * 4;
        ra[j] = *(const floatx4*)(Pg + (size_t)row * S_ + (k0 + 64) + c4);
      }
      #pragma unroll
      for (int j = 0; j < 4; j++)
        rb[j] = *(const floatx4*)(Bg + (size_t)(k0 + 64 + s0 + j) * D_ + d0);
    }
    #pragma unroll
    for (int kk = 0; kk < 2; kk++) {
      int kb = kk * 32 + ((lane >> 4) << 3);
      u16x8 a[4], bb[2];
      #pragma unroll
      for (int m = 0; m < 4; m++)
        a[m] = *(const u16x8*)&As[wr * 64 + m * 16 + (lane & 15)][kb];
      #pragma unroll
      for (int n = 0; n < 2; n++)
        bb[n] = *(const u16x8*)&BsT[wc * 32 + n * 16 + (lane & 15)][kb];
      #pragma unroll
      for (int m = 0; m < 4; m++)
        #pragma unroll
        for (int n = 0; n < 2; n++)
          acc[m][n] = mfma16(a[m], bb[n], acc[m][n]);
    }
    __syncthreads();
  }
  #pragma unroll
  for (int m = 0; m < 4; m++)
    #pragma unroll
    for (int n = 0; n < 2; n++)
      #pragma unroll
      for (int j = 0; j < 4; j++) {
        int t = wr * 64 + m * 16 + ((lane >> 4) << 2) + j;
        int d = dblk * 64 + wc * 32 + n * 16 + (lane & 15);
        cout[((size_t)b * T_ + t) * D_ + d] = acc[m][n][j];
      }
}

// ---------------------------------------------------------------------------
// K4: attn_h[t][b][n] = tanh( sum_k [c,src][b][t][k] * W[n][k] )
// Round-4 inner structure; GEOMETRY: 256 thr (4 waves 2x2), n-tile 64 ->
// grid (B,16) = 512 blocks = 2 blocks/CU ([c|src] is L2-resident per b).
// ---------------------------------------------------------------------------
__global__ __launch_bounds__(256, 2) void k_proj(
    const float* __restrict__ cbuf, const float* __restrict__ src,
    const float* __restrict__ w, float* __restrict__ out0)
{
  __shared__ unsigned short Ah[128][72];   // [t][k]
  __shared__ unsigned short Bh[64][72];    // [n][k]
  const int b = blockIdx.x, nblk = blockIdx.y;   // nblk: 64 n each
  const int tid = threadIdx.x, lane = tid & 63, wave = tid >> 6;
  const int wr = wave >> 1, wc = wave & 1;
  const float* Ca = cbuf + (size_t)b * T_ * D_;
  const float* Sa = src + (size_t)b * T_ * D_;

  f32x4 acc[4][2];
  #pragma unroll
  for (int m = 0; m < 4; m++)
    #pragma unroll
    for (int n = 0; n < 2; n++) acc[m][n] = (f32x4){0.f, 0.f, 0.f, 0.f};

  floatx4 ra[8], rb[4];
  #pragma unroll
  for (int j = 0; j < 8; j++) {
    int f4 = tid + 256 * j;
    int row = f4 >> 4, c4 = (f4 & 15) * 4;
    ra[j] = *(const floatx4*)(Ca + (size_t)row * D_ + c4);
  }
  #pragma unroll
  for (int j = 0; j < 4; j++) {
    int f4 = tid + 256 * j;
    int row = f4 >> 4, c4 = (f4 & 15) * 4;
    rb[j] = *(const floatx4*)(w + (size_t)(nblk * 64 + row) * (2 * D_) + c4);
  }

  for (int k0 = 0; k0 < 2 * D_; k0 += 64) {
    #pragma unroll
    for (int j = 0; j < 8; j++) {
      int f4 = tid + 256 * j;
      int row = f4 >> 4, c4 = (f4 & 15) * 4;
      u16x4 ah;
      #pragma unroll
      for (int i = 0; i < 4; i++) ah[i] = f2bf(ra[j][i]);
      *(u16x4*)&Ah[row][c4] = ah;
    }
    #pragma unroll
    for (int j = 0; j < 4; j++) {
      int f4 = tid + 256 * j;
      int row = f4 >> 4, c4 = (f4 & 15) * 4;
      u16x4 bh;
      #pragma unroll
      for (int i = 0; i < 4; i++) bh[i] = f2bf(rb[j][i]);
      *(u16x4*)&Bh[row][c4] = bh;
    }
    __syncthreads();
    if (k0 + 64 < 2 * D_) {
      int kn = k0 + 64;
      const float* Asrc = (kn < D_) ? (Ca + kn) : (Sa + (kn - D_));
      #pragma unroll
      for (int j = 0; j < 8; j++) {
        int f4 = tid + 256 * j;
        int row = f4 >> 4, c4 = (f4 & 15) * 4;
        ra[j] = *(const floatx4*)(Asrc + (size_t)row * D_ + c4);
      }
      #pragma unroll
      for (int j = 0; j < 4; j++) {
        int f4 = tid + 256 * j;
        int row = f4 >> 4, c4 = (f4 & 15) * 4;
        rb[j] = *(const floatx4*)(w + (size_t)(nblk * 64 + row) * (2 * D_) + kn + c4);
      }
    }
    #pragma unroll
    for (int kk = 0; kk < 2; kk++) {
      int kb = kk * 32 + ((lane >> 4) << 3);
      u16x8 a[4], bb[2];
      #pragma unroll
      for (int m = 0; m < 4; m++)
        a[m] = *(const u16x8*)&Ah[wr * 64 + m * 16 + (lane & 15)][kb];
      #pragma unroll
      for (int n = 0; n < 2; n++)
        bb[n] = *(const u16x8*)&Bh[wc * 32 + n * 16 + (lane & 15)][kb];
      #pragma unroll
      for (int m = 0; m < 4; m++)
        #pragma unroll
        for (int n = 0; n < 2; n++)
          acc[m][n] = mfma16(a[m], bb[n], acc[m][n]);
    }
    __syncthreads();
  }
  #pragma unroll
  for (int m = 0; m < 4; m++)
    #pragma unroll
    for (int n = 0; n < 2; n++)
      #pragma unroll
      for (int j = 0; j < 4; j++) {
        int t = wr * 64 + m * 16 + ((lane >> 4) << 2) + j;
        int d = nblk * 64 + wc * 32 + n * 16 + (lane & 15);
        out0[(size_t)t * (B_ * D_) + (size_t)b * D_ + d] = tanhf(acc[m][n][j]);
      }
}

extern "C" void kernel_launch(void* const* d_in, const int* in_sizes, int n_in,
                              void* d_out, int out_size, void* d_ws, size_t ws_size,
                              hipStream_t stream) {
  const float* src = (const float*)d_in[0];   // [B][T][D]
  const float* mb  = (const float*)d_in[1];   // [B][S][D]
  const float* w   = (const float*)d_in[2];   // [D][2D]
  const int*   len = (const int*)d_in[3];     // [B]

  float* out0 = (float*)d_out;                       // attn_h [T][B][D]
  float* out1 = out0 + (size_t)T_ * B_ * D_;         // align  [T][B][S]

  float* logits = (float*)d_ws;                      // [B][T][S] fp32
  float* cbuf   = logits + (size_t)B_ * T_ * S_;     // [B][T][D] fp32

  k_align  <<<dim3(B_, S_ / 128), 512, 0, stream>>>(src, mb, logits);
  k_softmax<<<dim3(B_ * T_),      256, 0, stream>>>(logits, len, out1);
  k_pv     <<<dim3(B_, D_ / 64),  256, 0, stream>>>(logits, mb, cbuf);
  k_proj   <<<dim3(B_, D_ / 64),  256, 0, stream>>>(cbuf, src, w, out0);
}

// Round 9
// 220.486 us; speedup vs baseline: 1.0699x; 1.0068x over previous
//
#include <hip/hip_runtime.h>
#include <hip/hip_bf16.h>
#include <stdint.h>

#define B_ 32
#define T_ 128
#define S_ 2048
#define D_ 1024

typedef float floatx4 __attribute__((ext_vector_type(4)));
typedef float f32x4 __attribute__((ext_vector_type(4)));
typedef unsigned short u16x4 __attribute__((ext_vector_type(4)));
typedef unsigned short u16x8 __attribute__((ext_vector_type(8)));
typedef __bf16 bf16x8 __attribute__((ext_vector_type(8)));

__device__ __forceinline__ unsigned short f2bf(float x){
  __hip_bfloat16 h = __float2bfloat16(x);
  return __builtin_bit_cast(unsigned short, h);
}
__device__ __forceinline__ float bf2f(unsigned short u){
  __hip_bfloat16 h = __builtin_bit_cast(__hip_bfloat16, u);
  return __bfloat162float(h);
}
__device__ __forceinline__ f32x4 mfma16(u16x8 a, u16x8 b, f32x4 c){
  return __builtin_amdgcn_mfma_f32_16x16x32_bf16(
      __builtin_bit_cast(bf16x8, a), __builtin_bit_cast(bf16x8, b), c, 0, 0, 0);
}

// ---------------------------------------------------------------------------
// K1: logits[b][t][s] = sum_d src[b][t][d] * mb[b][s][d]
// RNE hi/lo split x 3 MFMA (R4-verified math). NEW: double-buffered LDS with
// ONE barrier per K-step:
//   iter i: load tile i+1 -> regs ; MFMA <- buf[i&1] ; convert regs -> buf[(i+1)&1] ; bar
// Parity proof: buf written in iter i is first read in iter i+1 (barrier
// between); buf read in iter i was written in iter i-1 (barrier between);
// ra/rb dead at overwrite (converted previous iter). LDS kept at 64 KB
// (2 blocks/CU) via unpadded [128][32] panels + 16B-chunk XOR swizzle
// (chunk ^= (row>>1)&3) applied identically on writes (8B) and reads (16B).
// ---------------------------------------------------------------------------
__global__ __launch_bounds__(512, 4) void k_align(
    const float* __restrict__ src, const float* __restrict__ mb,
    float* __restrict__ logits)
{
  // [buf][panel: 0=Ah 1=Al 2=Bh 3=Bl][row][32 shorts], 64 KB total
  __shared__ unsigned short SH[2][4][128][32];
  const int b = blockIdx.x, sblk = blockIdx.y;
  const int tid = threadIdx.x, lane = tid & 63, wave = tid >> 6;
  const int wr = wave >> 2, wc = wave & 3;
  const float* Ag = src + (size_t)b * T_ * D_;
  const float* Bg = mb + (size_t)b * S_ * D_ + (size_t)sblk * 128 * D_;

  f32x4 acc[4][2];
  #pragma unroll
  for (int m = 0; m < 4; m++)
    #pragma unroll
    for (int n = 0; n < 2; n++) acc[m][n] = (f32x4){0.f, 0.f, 0.f, 0.f};

  // staging coords: 2 float4/thread, rows 0..127, k-cols 0..31
  // write short-offset: swizzle the 16B chunk index by (row>>1)&3
  const int r0 = tid >> 3;                    // j=0 row
  const int c40 = (tid & 7) * 4;              // j=0 k-col (shorts)
  const int sw0 = ((((c40 >> 3) ^ ((r0 >> 1) & 3)) << 3) | (c40 & 7));
  const int r1 = r0 + 64;                     // j=1 row
  const int sw1 = ((((c40 >> 3) ^ ((r1 >> 1) & 3)) << 3) | (c40 & 7));

  floatx4 ra[2], rb[2];
  ra[0] = *(const floatx4*)(Ag + (size_t)r0 * D_ + c40);
  ra[1] = *(const floatx4*)(Ag + (size_t)r1 * D_ + c40);
  rb[0] = *(const floatx4*)(Bg + (size_t)r0 * D_ + c40);
  rb[1] = *(const floatx4*)(Bg + (size_t)r1 * D_ + c40);

  // prologue: convert tile 0 -> buf 0
  {
    u16x4 ah, al, bh, bl;
    #pragma unroll
    for (int i = 0; i < 4; i++) {
      unsigned short h = f2bf(ra[0][i]); float hf = bf2f(h);
      ah[i] = h; al[i] = f2bf(ra[0][i] - hf);
      h = f2bf(rb[0][i]); hf = bf2f(h);
      bh[i] = h; bl[i] = f2bf(rb[0][i] - hf);
    }
    *(u16x4*)&SH[0][0][r0][sw0] = ah;
    *(u16x4*)&SH[0][1][r0][sw0] = al;
    *(u16x4*)&SH[0][2][r0][sw0] = bh;
    *(u16x4*)&SH[0][3][r0][sw0] = bl;
    #pragma unroll
    for (int i = 0; i < 4; i++) {
      unsigned short h = f2bf(ra[1][i]); float hf = bf2f(h);
      ah[i] = h; al[i] = f2bf(ra[1][i] - hf);
      h = f2bf(rb[1][i]); hf = bf2f(h);
      bh[i] = h; bl[i] = f2bf(rb[1][i] - hf);
    }
    *(u16x4*)&SH[0][0][r1][sw1] = ah;
    *(u16x4*)&SH[0][1][r1][sw1] = al;
    *(u16x4*)&SH[0][2][r1][sw1] = bh;
    *(u16x4*)&SH[0][3][r1][sw1] = bl;
  }
  __syncthreads();

  for (int it = 0; it < 32; ++it) {
    const int cur = it & 1, nxt = cur ^ 1;
    const bool more = (it + 1 < 32);
    // (1) issue loads for tile it+1 (in flight during MFMA phase)
    if (more) {
      const int k0 = (it + 1) * 32;
      ra[0] = *(const floatx4*)(Ag + (size_t)r0 * D_ + k0 + c40);
      ra[1] = *(const floatx4*)(Ag + (size_t)r1 * D_ + k0 + c40);
      rb[0] = *(const floatx4*)(Bg + (size_t)r0 * D_ + k0 + c40);
      rb[1] = *(const floatx4*)(Bg + (size_t)r1 * D_ + k0 + c40);
    }
    // (2) MFMA from buf[cur] (written iter it-1, barrier-separated)
    {
      const int kb = (lane >> 4) << 3;   // 0,8,16,24 (chunk-aligned)
      u16x8 a_h[4], a_l[4], b_h[2], b_l[2];
      #pragma unroll
      for (int m = 0; m < 4; m++) {
        int r = wr * 64 + m * 16 + (lane & 15);
        int kbs = (((kb >> 3) ^ ((r >> 1) & 3)) << 3);
        a_h[m] = *(const u16x8*)&SH[cur][0][r][kbs];
        a_l[m] = *(const u16x8*)&SH[cur][1][r][kbs];
      }
      #pragma unroll
      for (int n = 0; n < 2; n++) {
        int r = wc * 32 + n * 16 + (lane & 15);
        int kbs = (((kb >> 3) ^ ((r >> 1) & 3)) << 3);
        b_h[n] = *(const u16x8*)&SH[cur][2][r][kbs];
        b_l[n] = *(const u16x8*)&SH[cur][3][r][kbs];
      }
      #pragma unroll
      for (int m = 0; m < 4; m++)
        #pragma unroll
        for (int n = 0; n < 2; n++) {
          acc[m][n] = mfma16(a_h[m], b_h[n], acc[m][n]);
          acc[m][n] = mfma16(a_h[m], b_l[n], acc[m][n]);
          acc[m][n] = mfma16(a_l[m], b_h[n], acc[m][n]);
        }
    }
    // (3) convert tile it+1 -> buf[nxt] (last read in iter it-1; safe)
    if (more) {
      u16x4 ah, al, bh, bl;
      #pragma unroll
      for (int i = 0; i < 4; i++) {
        unsigned short h = f2bf(ra[0][i]); float hf = bf2f(h);
        ah[i] = h; al[i] = f2bf(ra[0][i] - hf);
        h = f2bf(rb[0][i]); hf = bf2f(h);
        bh[i] = h; bl[i] = f2bf(rb[0][i] - hf);
      }
      *(u16x4*)&SH[nxt][0][r0][sw0] = ah;
      *(u16x4*)&SH[nxt][1][r0][sw0] = al;
      *(u16x4*)&SH[nxt][2][r0][sw0] = bh;
      *(u16x4*)&SH[nxt][3][r0][sw0] = bl;
      #pragma unroll
      for (int i = 0; i < 4; i++) {
        unsigned short h = f2bf(ra[1][i]); float hf = bf2f(h);
        ah[i] = h; al[i] = f2bf(ra[1][i] - hf);
        h = f2bf(rb[1][i]); hf = bf2f(h);
        bh[i] = h; bl[i] = f2bf(rb[1][i] - hf);
      }
      *(u16x4*)&SH[nxt][0][r1][sw1] = ah;
      *(u16x4*)&SH[nxt][1][r1][sw1] = al;
      *(u16x4*)&SH[nxt][2][r1][sw1] = bh;
      *(u16x4*)&SH[nxt][3][r1][sw1] = bl;
    }
    __syncthreads();
  }

  #pragma unroll
  for (int m = 0; m < 4; m++)
    #pragma unroll
    for (int n = 0; n < 2; n++)
      #pragma unroll
      for (int j = 0; j < 4; j++) {
        int t = wr * 64 + m * 16 + ((lane >> 4) << 2) + j;
        int s = sblk * 128 + wc * 32 + n * 16 + (lane & 15);
        logits[((size_t)b * T_ + t) * S_ + s] = acc[m][n][j];
      }
}

// ---------------------------------------------------------------------------
// K2: masked softmax per (b,t) row (verified, unchanged).
// ---------------------------------------------------------------------------
__global__ __launch_bounds__(256) void k_softmax(
    float* __restrict__ logits, const int* __restrict__ lens,
    float* __restrict__ out1)
{
  const int bt = blockIdx.x;
  const int b = bt >> 7, t = bt & 127;
  const int probe = lens[1];               // 0 iff int64 layout (lens>=1)
  const int len = (probe == 0) ? lens[2 * b] : lens[b];
  float* row = logits + (size_t)bt * S_;
  const int tid = threadIdx.x, lane = tid & 63, wave = tid >> 6;

  floatx4 v[2];
  float mx = -3.0e38f;
  #pragma unroll
  for (int j = 0; j < 2; j++) {
    int f4 = tid + 256 * j;
    v[j] = *(const floatx4*)(row + f4 * 4);
    #pragma unroll
    for (int i = 0; i < 4; i++) {
      int s = f4 * 4 + i;
      if (s < len) mx = fmaxf(mx, v[j][i]);
    }
  }
  #pragma unroll
  for (int off = 1; off < 64; off <<= 1) mx = fmaxf(mx, __shfl_xor(mx, off));
  __shared__ float red[8];
  if (lane == 0) red[wave] = mx;
  __syncthreads();
  mx = fmaxf(fmaxf(red[0], red[1]), fmaxf(red[2], red[3]));

  float sum = 0.f;
  floatx4 e[2];
  #pragma unroll
  for (int j = 0; j < 2; j++) {
    int f4 = tid + 256 * j;
    #pragma unroll
    for (int i = 0; i < 4; i++) {
      int s = f4 * 4 + i;
      float ee = (s < len) ? __expf(v[j][i] - mx) : 0.f;
      e[j][i] = ee; sum += ee;
    }
  }
  #pragma unroll
  for (int off = 1; off < 64; off <<= 1) sum += __shfl_xor(sum, off);
  if (lane == 0) red[4 + wave] = sum;
  __syncthreads();
  sum = red[4] + red[5] + red[6] + red[7];
  const float inv = 1.0f / sum;

  float* orow = out1 + ((size_t)t * B_ + b) * S_;
  #pragma unroll
  for (int j = 0; j < 2; j++) {
    int f4 = tid + 256 * j;
    floatx4 o;
    #pragma unroll
    for (int i = 0; i < 4; i++) o[i] = e[j][i] * inv;
    *(floatx4*)(row + f4 * 4) = o;
    *(floatx4*)(orow + f4 * 4) = o;
  }
}

// ---------------------------------------------------------------------------
// K3: c[b][t][d] = sum_s p[b][t][s] * mb[b][s][d].  (R8-verified, unchanged)
// ---------------------------------------------------------------------------
__global__ __launch_bounds__(256, 2) void k_pv(
    const float* __restrict__ p, const float* __restrict__ mb,
    float* __restrict__ cout)
{
  __shared__ unsigned short As[128][72];   // [t][s]
  __shared__ unsigned short BsT[64][72];   // [d][s]
  const int b = blockIdx.x, dblk = blockIdx.y;   // dblk: 64 d each
  const int tid = threadIdx.x, lane = tid & 63, wave = tid >> 6;
  const int wr = wave >> 1, wc = wave & 1;       // 2x2 wave grid
  const float* Pg = p + (size_t)b * T_ * S_;
  const float* Bg = mb + (size_t)b * S_ * D_ + dblk * 64;

  f32x4 acc[4][2];
  #pragma unroll
  for (int m = 0; m < 4; m++)
    #pragma unroll
    for (int n = 0; n < 2; n++) acc[m][n] = (f32x4){0.f, 0.f, 0.f, 0.f};

  const int gs = tid & 15, gd = tid >> 4;  // transpose group: 4s x 4d
  const int s0 = gs * 4, d0 = gd * 4;      // both 0..60

  floatx4 ra[8], rb[4];
  #pragma unroll
  for (int j = 0; j < 8; j++) {
    int f4 = tid + 256 * j;
    int row = f4 >> 4, c4 = (f4 & 15) * 4;
    ra[j] = *(const floatx4*)(Pg + (size_t)row * S_ + c4);
  }
  #pragma unroll
  for (int j = 0; j < 4; j++)
    rb[j] = *(const floatx4*)(Bg + (size_t)(s0 + j) * D_ + d0);

  for (int k0 = 0; k0 < S_; k0 += 64) {
    #pragma unroll
    for (int j = 0; j < 8; j++) {
      int f4 = tid + 256 * j;
      int row = f4 >> 4, c4 = (f4 & 15) * 4;
      u16x4 ah;
      #pragma unroll
      for (int i = 0; i < 4; i++) ah[i] = f2bf(ra[j][i]);
      *(u16x4*)&As[row][c4] = ah;
    }
    #pragma unroll
    for (int jj = 0; jj < 4; jj++) {
      u16x4 w = { f2bf(rb[0][jj]), f2bf(rb[1][jj]), f2bf(rb[2][jj]), f2bf(rb[3][jj]) };
      *(u16x4*)&BsT[d0 + jj][s0] = w;
    }
    __syncthreads();
    if (k0 + 64 < S_) {
      #pragma unroll
      for (int j = 0; j < 8; j++) {
        int f4 = tid + 256 * j;
        int row = f4 >> 4, c4 = (f4 & 15) * 4;
        ra[j] = *(const floatx4*)(Pg + (size_t)row * S_ + (k0 + 64) + c4);
      }
      #pragma unroll
      for (int j = 0; j < 4; j++)
        rb[j] = *(const floatx4*)(Bg + (size_t)(k0 + 64 + s0 + j) * D_ + d0);
    }
    #pragma unroll
    for (int kk = 0; kk < 2; kk++) {
      int kb = kk * 32 + ((lane >> 4) << 3);
      u16x8 a[4], bb[2];
      #pragma unroll
      for (int m = 0; m < 4; m++)
        a[m] = *(const u16x8*)&As[wr * 64 + m * 16 + (lane & 15)][kb];
      #pragma unroll
      for (int n = 0; n < 2; n++)
        bb[n] = *(const u16x8*)&BsT[wc * 32 + n * 16 + (lane & 15)][kb];
      #pragma unroll
      for (int m = 0; m < 4; m++)
        #pragma unroll
        for (int n = 0; n < 2; n++)
          acc[m][n] = mfma16(a[m], bb[n], acc[m][n]);
    }
    __syncthreads();
  }
  #pragma unroll
  for (int m = 0; m < 4; m++)
    #pragma unroll
    for (int n = 0; n < 2; n++)
      #pragma unroll
      for (int j = 0; j < 4; j++) {
        int t = wr * 64 + m * 16 + ((lane >> 4) << 2) + j;
        int d = dblk * 64 + wc * 32 + n * 16 + (lane & 15);
        cout[((size_t)b * T_ + t) * D_ + d] = acc[m][n][j];
      }
}

// ---------------------------------------------------------------------------
// K4: attn_h[t][b][n] = tanh( sum_k [c,src][b][t][k] * W[n][k] )
// (R8-verified, unchanged)
// ---------------------------------------------------------------------------
__global__ __launch_bounds__(256, 2) void k_proj(
    const float* __restrict__ cbuf, const float* __restrict__ src,
    const float* __restrict__ w, float* __restrict__ out0)
{
  __shared__ unsigned short Ah[128][72];   // [t][k]
  __shared__ unsigned short Bh[64][72];    // [n][k]
  const int b = blockIdx.x, nblk = blockIdx.y;   // nblk: 64 n each
  const int tid = threadIdx.x, lane = tid & 63, wave = tid >> 6;
  const int wr = wave >> 1, wc = wave & 1;
  const float* Ca = cbuf + (size_t)b * T_ * D_;
  const float* Sa = src + (size_t)b * T_ * D_;

  f32x4 acc[4][2];
  #pragma unroll
  for (int m = 0; m < 4; m++)
    #pragma unroll
    for (int n = 0; n < 2; n++) acc[m][n] = (f32x4){0.f, 0.f, 0.f, 0.f};

  floatx4 ra[8], rb[4];
  #pragma unroll
  for (int j = 0; j < 8; j++) {
    int f4 = tid + 256 * j;
    int row = f4 >> 4, c4 = (f4 & 15) * 4;
    ra[j] = *(const floatx4*)(Ca + (size_t)row * D_ + c4);
  }
  #pragma unroll
  for (int j = 0; j < 4; j++) {
    int f4 = tid + 256 * j;
    int row = f4 >> 4, c4 = (f4 & 15) * 4;
    rb[j] = *(const floatx4*)(w + (size_t)(nblk * 64 + row) * (2 * D_) + c4);
  }

  for (int k0 = 0; k0 < 2 * D_; k0 += 64) {
    #pragma unroll
    for (int j = 0; j < 8; j++) {
      int f4 = tid + 256 * j;
      int row = f4 >> 4, c4 = (f4 & 15) * 4;
      u16x4 ah;
      #pragma unroll
      for (int i = 0; i < 4; i++) ah[i] = f2bf(ra[j][i]);
      *(u16x4*)&Ah[row][c4] = ah;
    }
    #pragma unroll
    for (int j = 0; j < 4; j++) {
      int f4 = tid + 256 * j;
      int row = f4 >> 4, c4 = (f4 & 15) * 4;
      u16x4 bh;
      #pragma unroll
      for (int i = 0; i < 4; i++) bh[i] = f2bf(rb[j][i]);
      *(u16x4*)&Bh[row][c4] = bh;
    }
    __syncthreads();
    if (k0 + 64 < 2 * D_) {
      int kn = k0 + 64;
      const float* Asrc = (kn < D_) ? (Ca + kn) : (Sa + (kn - D_));
      #pragma unroll
      for (int j = 0; j < 8; j++) {
        int f4 = tid + 256 * j;
        int row = f4 >> 4, c4 = (f4 & 15) * 4;
        ra[j] = *(const floatx4*)(Asrc + (size_t)row * D_ + c4);
      }
      #pragma unroll
      for (int j = 0; j < 4; j++) {
        int f4 = tid + 256 * j;
        int row = f4 >> 4, c4 = (f4 & 15) * 4;
        rb[j] = *(const floatx4*)(w + (size_t)(nblk * 64 + row) * (2 * D_) + kn + c4);
      }
    }
    #pragma unroll
    for (int kk = 0; kk < 2; kk++) {
      int kb = kk * 32 + ((lane >> 4) << 3);
      u16x8 a[4], bb[2];
      #pragma unroll
      for (int m = 0; m < 4; m++)
        a[m] = *(const u16x8*)&Ah[wr * 64 + m * 16 + (lane & 15)][kb];
      #pragma unroll
      for (int n = 0; n < 2; n++)
        bb[n] = *(const u16x8*)&Bh[wc * 32 + n * 16 + (lane & 15)][kb];
      #pragma unroll
      for (int m = 0; m < 4; m++)
        #pragma unroll
        for (int n = 0; n < 2; n++)
          acc[m][n] = mfma16(a[m], bb[n], acc[m][n]);
    }
    __syncthreads();
  }
  #pragma unroll
  for (int m = 0; m < 4; m++)
    #pragma unroll
    for (int n = 0; n < 2; n++)
      #pragma unroll
      for (int j = 0; j < 4; j++) {
        int t = wr * 64 + m * 16 + ((lane >> 4) << 2) + j;
        int d = nblk * 64 + wc * 32 + n * 16 + (lane & 15);
        out0[(size_t)t * (B_ * D_) + (size_t)b * D_ + d] = tanhf(acc[m][n][j]);
      }
}

extern "C" void kernel_launch(void* const* d_in, const int* in_sizes, int n_in,
                              void* d_out, int out_size, void* d_ws, size_t ws_size,
                              hipStream_t stream) {
  const float* src = (const float*)d_in[0];   // [B][T][D]
  const float* mb  = (const float*)d_in[1];   // [B][S][D]
  const float* w   = (const float*)d_in[2];   // [D][2D]
  const int*   len = (const int*)d_in[3];     // [B]

  float* out0 = (float*)d_out;                       // attn_h [T][B][D]
  float* out1 = out0 + (size_t)T_ * B_ * D_;         // align  [T][B][S]

  float* logits = (float*)d_ws;                      // [B][T][S] fp32
  float* cbuf   = logits + (size_t)B_ * T_ * S_;     // [B][T][D] fp32

  k_align  <<<dim3(B_, S_ / 128), 512, 0, stream>>>(src, mb, logits);
  k_softmax<<<dim3(B_ * T_),      256, 0, stream>>>(logits, len, out1);
  k_pv     <<<dim3(B_, D_ / 64),  256, 0, stream>>>(logits, mb, cbuf);
  k_proj   <<<dim3(B_, D_ / 64),  256, 0, stream>>>(cbuf, src, w, out0);
}

// Round 10
// 211.423 us; speedup vs baseline: 1.1158x; 1.0429x over previous
//
#include <hip/hip_runtime.h>
#include <hip/hip_bf16.h>
#include <stdint.h>

#define B_ 32
#define T_ 128
#define S_ 2048
#define D_ 1024

typedef float floatx4 __attribute__((ext_vector_type(4)));
typedef float f32x4 __attribute__((ext_vector_type(4)));
typedef unsigned short u16x4 __attribute__((ext_vector_type(4)));
typedef unsigned short u16x8 __attribute__((ext_vector_type(8)));
typedef __bf16 bf16x8 __attribute__((ext_vector_type(8)));

__device__ __forceinline__ unsigned short f2bf(float x){
  __hip_bfloat16 h = __float2bfloat16(x);
  return __builtin_bit_cast(unsigned short, h);
}
__device__ __forceinline__ float bf2f(unsigned short u){
  __hip_bfloat16 h = __builtin_bit_cast(__hip_bfloat16, u);
  return __bfloat162float(h);
}
__device__ __forceinline__ f32x4 mfma16(u16x8 a, u16x8 b, f32x4 c){
  return __builtin_amdgcn_mfma_f32_16x16x32_bf16(
      __builtin_bit_cast(bf16x8, a), __builtin_bit_cast(bf16x8, b), c, 0, 0, 0);
}

// ---------------------------------------------------------------------------
// K1: logits[b][t][s] = sum_d src[b][t][d] * mb[b][s][d]
// R9-VERIFIED: RNE hi/lo split x 3 MFMA, double-buffered LDS, one barrier
// per K-step, 16B-chunk XOR swizzle, 64 KB LDS -> 2 blocks/CU.
// ---------------------------------------------------------------------------
__global__ __launch_bounds__(512, 4) void k_align(
    const float* __restrict__ src, const float* __restrict__ mb,
    float* __restrict__ logits)
{
  __shared__ unsigned short SH[2][4][128][32];
  const int b = blockIdx.x, sblk = blockIdx.y;
  const int tid = threadIdx.x, lane = tid & 63, wave = tid >> 6;
  const int wr = wave >> 2, wc = wave & 3;
  const float* Ag = src + (size_t)b * T_ * D_;
  const float* Bg = mb + (size_t)b * S_ * D_ + (size_t)sblk * 128 * D_;

  f32x4 acc[4][2];
  #pragma unroll
  for (int m = 0; m < 4; m++)
    #pragma unroll
    for (int n = 0; n < 2; n++) acc[m][n] = (f32x4){0.f, 0.f, 0.f, 0.f};

  const int r0 = tid >> 3;
  const int c40 = (tid & 7) * 4;
  const int sw0 = ((((c40 >> 3) ^ ((r0 >> 1) & 3)) << 3) | (c40 & 7));
  const int r1 = r0 + 64;
  const int sw1 = ((((c40 >> 3) ^ ((r1 >> 1) & 3)) << 3) | (c40 & 7));

  floatx4 ra[2], rb[2];
  ra[0] = *(const floatx4*)(Ag + (size_t)r0 * D_ + c40);
  ra[1] = *(const floatx4*)(Ag + (size_t)r1 * D_ + c40);
  rb[0] = *(const floatx4*)(Bg + (size_t)r0 * D_ + c40);
  rb[1] = *(const floatx4*)(Bg + (size_t)r1 * D_ + c40);

  {
    u16x4 ah, al, bh, bl;
    #pragma unroll
    for (int i = 0; i < 4; i++) {
      unsigned short h = f2bf(ra[0][i]); float hf = bf2f(h);
      ah[i] = h; al[i] = f2bf(ra[0][i] - hf);
      h = f2bf(rb[0][i]); hf = bf2f(h);
      bh[i] = h; bl[i] = f2bf(rb[0][i] - hf);
    }
    *(u16x4*)&SH[0][0][r0][sw0] = ah;
    *(u16x4*)&SH[0][1][r0][sw0] = al;
    *(u16x4*)&SH[0][2][r0][sw0] = bh;
    *(u16x4*)&SH[0][3][r0][sw0] = bl;
    #pragma unroll
    for (int i = 0; i < 4; i++) {
      unsigned short h = f2bf(ra[1][i]); float hf = bf2f(h);
      ah[i] = h; al[i] = f2bf(ra[1][i] - hf);
      h = f2bf(rb[1][i]); hf = bf2f(h);
      bh[i] = h; bl[i] = f2bf(rb[1][i] - hf);
    }
    *(u16x4*)&SH[0][0][r1][sw1] = ah;
    *(u16x4*)&SH[0][1][r1][sw1] = al;
    *(u16x4*)&SH[0][2][r1][sw1] = bh;
    *(u16x4*)&SH[0][3][r1][sw1] = bl;
  }
  __syncthreads();

  for (int it = 0; it < 32; ++it) {
    const int cur = it & 1, nxt = cur ^ 1;
    const bool more = (it + 1 < 32);
    if (more) {
      const int k0 = (it + 1) * 32;
      ra[0] = *(const floatx4*)(Ag + (size_t)r0 * D_ + k0 + c40);
      ra[1] = *(const floatx4*)(Ag + (size_t)r1 * D_ + k0 + c40);
      rb[0] = *(const floatx4*)(Bg + (size_t)r0 * D_ + k0 + c40);
      rb[1] = *(const floatx4*)(Bg + (size_t)r1 * D_ + k0 + c40);
    }
    {
      const int kb = (lane >> 4) << 3;
      u16x8 a_h[4], a_l[4], b_h[2], b_l[2];
      #pragma unroll
      for (int m = 0; m < 4; m++) {
        int r = wr * 64 + m * 16 + (lane & 15);
        int kbs = (((kb >> 3) ^ ((r >> 1) & 3)) << 3);
        a_h[m] = *(const u16x8*)&SH[cur][0][r][kbs];
        a_l[m] = *(const u16x8*)&SH[cur][1][r][kbs];
      }
      #pragma unroll
      for (int n = 0; n < 2; n++) {
        int r = wc * 32 + n * 16 + (lane & 15);
        int kbs = (((kb >> 3) ^ ((r >> 1) & 3)) << 3);
        b_h[n] = *(const u16x8*)&SH[cur][2][r][kbs];
        b_l[n] = *(const u16x8*)&SH[cur][3][r][kbs];
      }
      #pragma unroll
      for (int m = 0; m < 4; m++)
        #pragma unroll
        for (int n = 0; n < 2; n++) {
          acc[m][n] = mfma16(a_h[m], b_h[n], acc[m][n]);
          acc[m][n] = mfma16(a_h[m], b_l[n], acc[m][n]);
          acc[m][n] = mfma16(a_l[m], b_h[n], acc[m][n]);
        }
    }
    if (more) {
      u16x4 ah, al, bh, bl;
      #pragma unroll
      for (int i = 0; i < 4; i++) {
        unsigned short h = f2bf(ra[0][i]); float hf = bf2f(h);
        ah[i] = h; al[i] = f2bf(ra[0][i] - hf);
        h = f2bf(rb[0][i]); hf = bf2f(h);
        bh[i] = h; bl[i] = f2bf(rb[0][i] - hf);
      }
      *(u16x4*)&SH[nxt][0][r0][sw0] = ah;
      *(u16x4*)&SH[nxt][1][r0][sw0] = al;
      *(u16x4*)&SH[nxt][2][r0][sw0] = bh;
      *(u16x4*)&SH[nxt][3][r0][sw0] = bl;
      #pragma unroll
      for (int i = 0; i < 4; i++) {
        unsigned short h = f2bf(ra[1][i]); float hf = bf2f(h);
        ah[i] = h; al[i] = f2bf(ra[1][i] - hf);
        h = f2bf(rb[1][i]); hf = bf2f(h);
        bh[i] = h; bl[i] = f2bf(rb[1][i] - hf);
      }
      *(u16x4*)&SH[nxt][0][r1][sw1] = ah;
      *(u16x4*)&SH[nxt][1][r1][sw1] = al;
      *(u16x4*)&SH[nxt][2][r1][sw1] = bh;
      *(u16x4*)&SH[nxt][3][r1][sw1] = bl;
    }
    __syncthreads();
  }

  #pragma unroll
  for (int m = 0; m < 4; m++)
    #pragma unroll
    for (int n = 0; n < 2; n++)
      #pragma unroll
      for (int j = 0; j < 4; j++) {
        int t = wr * 64 + m * 16 + ((lane >> 4) << 2) + j;
        int s = sblk * 128 + wc * 32 + n * 16 + (lane & 15);
        logits[((size_t)b * T_ + t) * S_ + s] = acc[m][n][j];
      }
}

// ---------------------------------------------------------------------------
// K2: masked softmax per (b,t) row. Writes out1[t][b][s] fp32 (output) and
// pbf[b][t][s] BF16 (handoff to K3 — same value path as before, since K3
// converted p to bf16 anyway). The fp32 in-place p write is dropped.
// ---------------------------------------------------------------------------
__global__ __launch_bounds__(256) void k_softmax(
    const float* __restrict__ logits, const int* __restrict__ lens,
    float* __restrict__ out1, unsigned short* __restrict__ pbf)
{
  const int bt = blockIdx.x;
  const int b = bt >> 7, t = bt & 127;
  const int probe = lens[1];               // 0 iff int64 layout (lens>=1)
  const int len = (probe == 0) ? lens[2 * b] : lens[b];
  const float* row = logits + (size_t)bt * S_;
  const int tid = threadIdx.x, lane = tid & 63, wave = tid >> 6;

  floatx4 v[2];
  float mx = -3.0e38f;
  #pragma unroll
  for (int j = 0; j < 2; j++) {
    int f4 = tid + 256 * j;
    v[j] = *(const floatx4*)(row + f4 * 4);
    #pragma unroll
    for (int i = 0; i < 4; i++) {
      int s = f4 * 4 + i;
      if (s < len) mx = fmaxf(mx, v[j][i]);
    }
  }
  #pragma unroll
  for (int off = 1; off < 64; off <<= 1) mx = fmaxf(mx, __shfl_xor(mx, off));
  __shared__ float red[8];
  if (lane == 0) red[wave] = mx;
  __syncthreads();
  mx = fmaxf(fmaxf(red[0], red[1]), fmaxf(red[2], red[3]));

  float sum = 0.f;
  floatx4 e[2];
  #pragma unroll
  for (int j = 0; j < 2; j++) {
    int f4 = tid + 256 * j;
    #pragma unroll
    for (int i = 0; i < 4; i++) {
      int s = f4 * 4 + i;
      float ee = (s < len) ? __expf(v[j][i] - mx) : 0.f;
      e[j][i] = ee; sum += ee;
    }
  }
  #pragma unroll
  for (int off = 1; off < 64; off <<= 1) sum += __shfl_xor(sum, off);
  if (lane == 0) red[4 + wave] = sum;
  __syncthreads();
  sum = red[4] + red[5] + red[6] + red[7];
  const float inv = 1.0f / sum;

  float* orow = out1 + ((size_t)t * B_ + b) * S_;
  unsigned short* prow = pbf + (size_t)bt * S_;
  #pragma unroll
  for (int j = 0; j < 2; j++) {
    int f4 = tid + 256 * j;
    floatx4 o;
    u16x4 pk;
    #pragma unroll
    for (int i = 0; i < 4; i++) { o[i] = e[j][i] * inv; pk[i] = f2bf(o[i]); }
    *(floatx4*)(orow + f4 * 4) = o;   // output, [t][b][s] fp32
    *(u16x4*)(prow + f4 * 4) = pk;    // handoff, [b][t][s] bf16
  }
}

// ---------------------------------------------------------------------------
// K3: c[b][t][d] = sum_s p[b][t][s] * mb[b][s][d].
// R8-verified geometry (256 thr, 2x2 waves, d-tile 64, 2 blocks/CU).
// A operand now BF16 from k_softmax: staging = pure 16B copies (no convert).
// ---------------------------------------------------------------------------
__global__ __launch_bounds__(256, 2) void k_pv(
    const unsigned short* __restrict__ pbf, const float* __restrict__ mb,
    float* __restrict__ cout)
{
  __shared__ unsigned short As[128][72];   // [t][s]
  __shared__ unsigned short BsT[64][72];   // [d][s]
  const int b = blockIdx.x, dblk = blockIdx.y;   // dblk: 64 d each
  const int tid = threadIdx.x, lane = tid & 63, wave = tid >> 6;
  const int wr = wave >> 1, wc = wave & 1;       // 2x2 wave grid
  const unsigned short* Pg = pbf + (size_t)b * T_ * S_;
  const float* Bg = mb + (size_t)b * S_ * D_ + dblk * 64;

  f32x4 acc[4][2];
  #pragma unroll
  for (int m = 0; m < 4; m++)
    #pragma unroll
    for (int n = 0; n < 2; n++) acc[m][n] = (f32x4){0.f, 0.f, 0.f, 0.f};

  const int gs = tid & 15, gd = tid >> 4;  // transpose group: 4s x 4d
  const int s0 = gs * 4, d0 = gd * 4;      // both 0..60

  // A: [128 rows][64 shorts] per K-step = 1024 16B-chunks, 4/thread
  u16x8 ra[4];
  floatx4 rb[4];
  #pragma unroll
  for (int j = 0; j < 4; j++) {
    int g = tid + 256 * j;
    int row = g >> 3, c8 = (g & 7) * 8;
    ra[j] = *(const u16x8*)(Pg + (size_t)row * S_ + c8);
  }
  #pragma unroll
  for (int j = 0; j < 4; j++)
    rb[j] = *(const floatx4*)(Bg + (size_t)(s0 + j) * D_ + d0);

  for (int k0 = 0; k0 < S_; k0 += 64) {
    #pragma unroll
    for (int j = 0; j < 4; j++) {
      int g = tid + 256 * j;
      int row = g >> 3, c8 = (g & 7) * 8;
      *(u16x8*)&As[row][c8] = ra[j];
    }
    #pragma unroll
    for (int jj = 0; jj < 4; jj++) {
      u16x4 w = { f2bf(rb[0][jj]), f2bf(rb[1][jj]), f2bf(rb[2][jj]), f2bf(rb[3][jj]) };
      *(u16x4*)&BsT[d0 + jj][s0] = w;
    }
    __syncthreads();
    if (k0 + 64 < S_) {
      #pragma unroll
      for (int j = 0; j < 4; j++) {
        int g = tid + 256 * j;
        int row = g >> 3, c8 = (g & 7) * 8;
        ra[j] = *(const u16x8*)(Pg + (size_t)row * S_ + (k0 + 64) + c8);
      }
      #pragma unroll
      for (int j = 0; j < 4; j++)
        rb[j] = *(const floatx4*)(Bg + (size_t)(k0 + 64 + s0 + j) * D_ + d0);
    }
    #pragma unroll
    for (int kk = 0; kk < 2; kk++) {
      int kb = kk * 32 + ((lane >> 4) << 3);
      u16x8 a[4], bb[2];
      #pragma unroll
      for (int m = 0; m < 4; m++)
        a[m] = *(const u16x8*)&As[wr * 64 + m * 16 + (lane & 15)][kb];
      #pragma unroll
      for (int n = 0; n < 2; n++)
        bb[n] = *(const u16x8*)&BsT[wc * 32 + n * 16 + (lane & 15)][kb];
      #pragma unroll
      for (int m = 0; m < 4; m++)
        #pragma unroll
        for (int n = 0; n < 2; n++)
          acc[m][n] = mfma16(a[m], bb[n], acc[m][n]);
    }
    __syncthreads();
  }
  #pragma unroll
  for (int m = 0; m < 4; m++)
    #pragma unroll
    for (int n = 0; n < 2; n++)
      #pragma unroll
      for (int j = 0; j < 4; j++) {
        int t = wr * 64 + m * 16 + ((lane >> 4) << 2) + j;
        int d = dblk * 64 + wc * 32 + n * 16 + (lane & 15);
        cout[((size_t)b * T_ + t) * D_ + d] = acc[m][n][j];
      }
}

// ---------------------------------------------------------------------------
// K4: attn_h[t][b][n] = tanh( sum_k [c,src][b][t][k] * W[n][k] )
// (R8-verified, unchanged)
// ---------------------------------------------------------------------------
__global__ __launch_bounds__(256, 2) void k_proj(
    const float* __restrict__ cbuf, const float* __restrict__ src,
    const float* __restrict__ w, float* __restrict__ out0)
{
  __shared__ unsigned short Ah[128][72];   // [t][k]
  __shared__ unsigned short Bh[64][72];    // [n][k]
  const int b = blockIdx.x, nblk = blockIdx.y;   // nblk: 64 n each
  const int tid = threadIdx.x, lane = tid & 63, wave = tid >> 6;
  const int wr = wave >> 1, wc = wave & 1;
  const float* Ca = cbuf + (size_t)b * T_ * D_;
  const float* Sa = src + (size_t)b * T_ * D_;

  f32x4 acc[4][2];
  #pragma unroll
  for (int m = 0; m < 4; m++)
    #pragma unroll
    for (int n = 0; n < 2; n++) acc[m][n] = (f32x4){0.f, 0.f, 0.f, 0.f};

  floatx4 ra[8], rb[4];
  #pragma unroll
  for (int j = 0; j < 8; j++) {
    int f4 = tid + 256 * j;
    int row = f4 >> 4, c4 = (f4 & 15) * 4;
    ra[j] = *(const floatx4*)(Ca + (size_t)row * D_ + c4);
  }
  #pragma unroll
  for (int j = 0; j < 4; j++) {
    int f4 = tid + 256 * j;
    int row = f4 >> 4, c4 = (f4 & 15) * 4;
    rb[j] = *(const floatx4*)(w + (size_t)(nblk * 64 + row) * (2 * D_) + c4);
  }

  for (int k0 = 0; k0 < 2 * D_; k0 += 64) {
    #pragma unroll
    for (int j = 0; j < 8; j++) {
      int f4 = tid + 256 * j;
      int row = f4 >> 4, c4 = (f4 & 15) * 4;
      u16x4 ah;
      #pragma unroll
      for (int i = 0; i < 4; i++) ah[i] = f2bf(ra[j][i]);
      *(u16x4*)&Ah[row][c4] = ah;
    }
    #pragma unroll
    for (int j = 0; j < 4; j++) {
      int f4 = tid + 256 * j;
      int row = f4 >> 4, c4 = (f4 & 15) * 4;
      u16x4 bh;
      #pragma unroll
      for (int i = 0; i < 4; i++) bh[i] = f2bf(rb[j][i]);
      *(u16x4*)&Bh[row][c4] = bh;
    }
    __syncthreads();
    if (k0 + 64 < 2 * D_) {
      int kn = k0 + 64;
      const float* Asrc = (kn < D_) ? (Ca + kn) : (Sa + (kn - D_));
      #pragma unroll
      for (int j = 0; j < 8; j++) {
        int f4 = tid + 256 * j;
        int row = f4 >> 4, c4 = (f4 & 15) * 4;
        ra[j] = *(const floatx4*)(Asrc + (size_t)row * D_ + c4);
      }
      #pragma unroll
      for (int j = 0; j < 4; j++) {
        int f4 = tid + 256 * j;
        int row = f4 >> 4, c4 = (f4 & 15) * 4;
        rb[j] = *(const floatx4*)(w + (size_t)(nblk * 64 + row) * (2 * D_) + kn + c4);
      }
    }
    #pragma unroll
    for (int kk = 0; kk < 2; kk++) {
      int kb = kk * 32 + ((lane >> 4) << 3);
      u16x8 a[4], bb[2];
      #pragma unroll
      for (int m = 0; m < 4; m++)
        a[m] = *(const u16x8*)&Ah[wr * 64 + m * 16 + (lane & 15)][kb];
      #pragma unroll
      for (int n = 0; n < 2; n++)
        bb[n] = *(const u16x8*)&Bh[wc * 32 + n * 16 + (lane & 15)][kb];
      #pragma unroll
      for (int m = 0; m < 4; m++)
        #pragma unroll
        for (int n = 0; n < 2; n++)
          acc[m][n] = mfma16(a[m], bb[n], acc[m][n]);
    }
    __syncthreads();
  }
  #pragma unroll
  for (int m = 0; m < 4; m++)
    #pragma unroll
    for (int n = 0; n < 2; n++)
      #pragma unroll
      for (int j = 0; j < 4; j++) {
        int t = wr * 64 + m * 16 + ((lane >> 4) << 2) + j;
        int d = nblk * 64 + wc * 32 + n * 16 + (lane & 15);
        out0[(size_t)t * (B_ * D_) + (size_t)b * D_ + d] = tanhf(acc[m][n][j]);
      }
}

extern "C" void kernel_launch(void* const* d_in, const int* in_sizes, int n_in,
                              void* d_out, int out_size, void* d_ws, size_t ws_size,
                              hipStream_t stream) {
  const float* src = (const float*)d_in[0];   // [B][T][D]
  const float* mb  = (const float*)d_in[1];   // [B][S][D]
  const float* w   = (const float*)d_in[2];   // [D][2D]
  const int*   len = (const int*)d_in[3];     // [B]

  float* out0 = (float*)d_out;                       // attn_h [T][B][D]
  float* out1 = out0 + (size_t)T_ * B_ * D_;         // align  [T][B][S]

  float* logits = (float*)d_ws;                        // [B][T][S] fp32
  float* cbuf   = logits + (size_t)B_ * T_ * S_;       // [B][T][D] fp32
  unsigned short* pbf =
      (unsigned short*)(cbuf + (size_t)B_ * T_ * D_);  // [B][T][S] bf16

  k_align  <<<dim3(B_, S_ / 128), 512, 0, stream>>>(src, mb, logits);
  k_softmax<<<dim3(B_ * T_),      256, 0, stream>>>(logits, len, out1, pbf);
  k_pv     <<<dim3(B_, D_ / 64),  256, 0, stream>>>(pbf, mb, cbuf);
  k_proj   <<<dim3(B_, D_ / 64),  256, 0, stream>>>(cbuf, src, w, out0);
}